// Round 1
// baseline (369.783 us; speedup 1.0000x reference)
//
#include <hip/hip_runtime.h>
#include <hip/hip_bf16.h>

// B=4, N=1024, E=256, H=8, D=32. Float tensors may be bf16 OR fp32 in d_in /
// d_out (detected at runtime on-device); adj is int32.
// Output: x_out [4,1024,256] then e_out [4,1024,1024] (element offsets).
//
// ws float offsets:
//   [0 .. 196608)   : 6 weight matrices, transposed, bf16, quad-interleaved
//                     matrix m at ushort offset m*65536; element (e,o) at
//                     ((e>>2)*256 + o)*4 + (e&3).  m: 0=Wcat 1=LIN 2=WQ 3=WK 4=WV 5=WO
#define BIAS_OFF 196608   // lin_b, bq, bk, bv, bo, a1, a2  (7*256 fp32)
#define S1_OFF   198400   // [h][4096]
#define S2_OFF   231168
#define CS_OFF   263936   // 32768: column partial sums+sumsq (reused twice)
#define ST1_OFF  296704   // mean[1024] + inv[1024]
#define ST2_OFF  298752
#define A_OFF    300800   // WhT bf16 [h][b][d][n] (2 MB) -> later Q,o fp32 head-major
#define MX_OFF   825088   // A_OFF+524288: softmax row max  [h][4096] (dead before Q)
#define RS_OFF   857856   // softmax row 1/sum              [h][4096]
#define B_OFF    1349376  // 4 MB: rownorm(xa)     -> later K bf16 head-major [b][h][n][32]
#define C_OFF    2397952  // 4 MB: raw xa, then rownorm(lin) -> later V^T bf16 hm [b][h][d][n]
#define FLAG_F   3446528  // int: 1 = bf16 tensors, 0 = fp32 tensors
// end 3446529 floats = 13.8 MB

#define NEGC (-9.0e15f)

typedef __attribute__((ext_vector_type(8))) short bf16x8s;
typedef __attribute__((ext_vector_type(4))) float f32x4;

static __device__ __forceinline__ float bf2f(unsigned short u) {
  union { unsigned int i; float f; } v; v.i = ((unsigned int)u) << 16; return v.f;
}
static __device__ __forceinline__ unsigned short f2bf(float f) {
  union { float f; unsigned int u; } v; v.f = f;
  unsigned int r = (v.u + 0x7FFFu + ((v.u >> 16) & 1u)) >> 16;   // RNE
  return (unsigned short)r;
}
static __device__ __forceinline__ float ldin(const void* p, long i, int bf) {
  return bf ? bf2f(((const unsigned short*)p)[i]) : ((const float*)p)[i];
}
static __device__ __forceinline__ unsigned short rdbf(const void* p, long i, int bf) {
  if (bf) return ((const unsigned short*)p)[i];
  return f2bf(((const float*)p)[i]);
}
static __device__ __forceinline__ void stout(void* p, long i, float v, int bf) {
  if (bf) ((unsigned short*)p)[i] = f2bf(v);
  else    ((float*)p)[i] = v;
}

// ---------------- dtype detector -------------------------------------------
__global__ __launch_bounds__(64) void detect_kernel(const unsigned short* x, int* flag) {
  int lane = threadIdx.x;
  unsigned short u = x[2 * lane];
  int e = (u >> 7) & 0xFF;
  bool good = (e >= 100 && e <= 140);
  unsigned long long m = __ballot(good);
  if (lane == 0) *flag = (__popcll(m) >= 48) ? 1 : 0;
}

// ---------------- prep: weights -> transposed quad bf16; biases -> fp32 ----
__global__ __launch_bounds__(256) void prep_kernel(
    const void* wg, const void* lin_w, const void* inp_w, const void* out_w,
    const void* lin_b, const void* inp_b, const void* out_b,
    const void* a1, const void* a2, float* ws, const int* flagp) {
  const int bf = *flagp;
  unsigned short* wbf = (unsigned short*)ws;
  int t = threadIdx.x;
  int f = blockIdx.x;
  int m = blockIdx.y;
  int dst = m*65536 + ((f >> 2)*256 + t)*4 + (f & 3);
  if (m == 0) {
    int h = t >> 5, d = t & 31;
    wbf[dst] = rdbf(wg, h*8192 + f*32 + d, bf);
  } else if (m == 1) wbf[dst] = rdbf(lin_w, t*256 + f, bf);
  else if (m == 2)   wbf[dst] = rdbf(inp_w, t*256 + f, bf);
  else if (m == 3)   wbf[dst] = rdbf(inp_w, (256 + t)*256 + f, bf);
  else if (m == 4)   wbf[dst] = rdbf(inp_w, (512 + t)*256 + f, bf);
  else if (m == 5)   wbf[dst] = rdbf(out_w, t*256 + f, bf);
  else if (f == 0) {
    ws[BIAS_OFF + t]        = ldin(lin_b, t, bf);
    ws[BIAS_OFF + 256 + t]  = ldin(inp_b, t, bf);
    ws[BIAS_OFF + 512 + t]  = ldin(inp_b, 256 + t, bf);
    ws[BIAS_OFF + 768 + t]  = ldin(inp_b, 512 + t, bf);
    ws[BIAS_OFF + 1024 + t] = ldin(out_b, t, bf);
    ws[BIAS_OFF + 1280 + t] = ldin(a1, t, bf);
    ws[BIAS_OFF + 1536 + t] = ldin(a2, t, bf);
  }
}

// -------- Wh = x @ Wcat -> WhT bf16 [h][b][d][n]; s1/s2 head reductions ----
__global__ __launch_bounds__(256) void whs_kernel(const void* x, float* ws,
                                                  const int* flagp) {
  const int bf = *flagp;
  int t = threadIdx.x;
  int r0 = blockIdx.x * 8;
  __shared__ __align__(16) float U[8][256];
  #pragma unroll
  for (int r = 0; r < 8; ++r)
    U[r][t] = ldin(x, (long)(r0 + r)*256 + t, bf);
  __syncthreads();
  const ushort4* w4 = (const ushort4*)ws;
  float acc[8] = {0,0,0,0,0,0,0,0};
  for (int e4 = 0; e4 < 64; ++e4) {
    ushort4 u = w4[e4*256 + t];
    float w0 = bf2f(u.x), w1 = bf2f(u.y), w2 = bf2f(u.z), w3 = bf2f(u.w);
    #pragma unroll
    for (int r = 0; r < 8; ++r) {
      float4 uu = *(const float4*)&U[r][e4*4];
      acc[r] += uu.x*w0 + uu.y*w1 + uu.z*w2 + uu.w*w3;
    }
  }
  int h = t >> 5, d = t & 31;
  float a1v = ws[BIAS_OFF + 1280 + t];
  float a2v = ws[BIAS_OFF + 1536 + t];
  unsigned short wvals[8];
  #pragma unroll
  for (int r = 0; r < 8; ++r) {
    int row = r0 + r;
    wvals[r] = f2bf(acc[r]);
    float p1 = acc[r]*a1v, p2 = acc[r]*a2v;
    #pragma unroll
    for (int off = 16; off > 0; off >>= 1) {
      p1 += __shfl_xor(p1, off, 32);
      p2 += __shfl_xor(p2, off, 32);
    }
    if (d == 0) {
      ws[S1_OFF + h*4096 + row] = p1;
      ws[S2_OFF + h*4096 + row] = p2;
    }
  }
  // WhT[h][b][d][n], 8 contiguous n per thread (16B store)
  {
    unsigned short* wht = (unsigned short*)(ws + A_OFF);
    int bb = r0 >> 10, nn = r0 & 1023;
    *(bf16x8s*)(wht + ((long)((h*4 + bb)*32 + d))*1024 + nn) = *(bf16x8s*)wvals;
  }
}

// ------- graph attention, HEAD-SPLIT: one (b, 4-row group, head) per block -
// Grid 8192 = 4b x 256 groups x 8h; h in low 3 bits (XCD-L2 locality on WhT).
// Softmax register-resident (wave w owns row w); P bf16 in Pb; PV via
// mfma_f32_16x16x32_bf16 against WhT (4 real rows dup x4). Writes:
//   C region: raw xa slice  xa[b,n,h*32+d] = x + leaky(PV)
//   MX/RS: per-(h,row) softmax max and 1/sum (consumed by eout_kernel)
#define PB_S 1032    // Pb row stride (ushorts); 2064B = 129*16, rows +4 banks
__global__ __launch_bounds__(256) void attn1a_kernel(const void* x, const int* adj,
                                                     float* ws, const int* flagp) {
  const int bf = *flagp;
  int t = threadIdx.x;
  int gid = blockIdx.x;
  int h = gid & 7;
  int b = (gid >> 3) & 3;
  int n0 = (gid >> 5) * 4;
  __shared__ __align__(16) float s2s[1024];
  __shared__ __align__(16) unsigned short Pb[4][PB_S];
  __shared__ __align__(16) float opart[4][4][16];
  int w = t >> 6, lane = t & 63;
  int fm = lane & 15, quad = lane >> 4;
  const float* s2p = ws + S2_OFF + h*4096 + b*1024;
  #pragma unroll
  for (int j = 0; j < 4; ++j) s2s[t + 256*j] = s2p[t + 256*j];
  __syncthreads();
  // ---- softmax for row (n0 + w), head h: register resident ----------------
  {
    float s1v = ws[S1_OFF + h*4096 + b*1024 + n0 + w];
    const int* arow = adj + (long)(b*1024 + n0 + w)*1024;
    float p[16];
    float mx = -3.4e38f;
    #pragma unroll
    for (int j = 0; j < 16; ++j) {
      int m = lane + 64*j;
      float ev = s1v + s2s[m];
      ev = (ev >= 0.0f) ? ev : 0.1f*ev;
      ev = (arow[m] > 0) ? ev : NEGC;
      p[j] = ev;
      mx = fmaxf(mx, ev);
    }
    #pragma unroll
    for (int off = 32; off > 0; off >>= 1) mx = fmaxf(mx, __shfl_xor(mx, off));
    float s = 0.0f;
    #pragma unroll
    for (int j = 0; j < 16; ++j) { p[j] = __expf(p[j] - mx); s += p[j]; }
    #pragma unroll
    for (int off = 32; off > 0; off >>= 1) s += __shfl_xor(s, off);
    float rs = 1.0f / s;
    #pragma unroll
    for (int j = 0; j < 16; ++j)
      Pb[w][lane + 64*j] = f2bf(p[j] * rs);
    if (lane == 0) {
      ws[MX_OFF + h*4096 + b*1024 + n0 + w] = mx;
      ws[RS_OFF + h*4096 + b*1024 + n0 + w] = rs;
    }
  }
  __syncthreads();
  // ---- PV via MFMA: wave w -> ntile (w&1), k-tiles (w>>1)*16 .. +15 -------
  {
    const unsigned short* wht = (const unsigned short*)(ws + A_OFF);
    int ntile = w & 1;
    int ktbase = (w >> 1) * 16;
    int vd = ntile*16 + fm;
    const unsigned short* wrow = wht + ((long)((h*4 + b)*32 + vd))*1024;
    f32x4 acc = {0.0f, 0.0f, 0.0f, 0.0f};
    #pragma unroll
    for (int kt2 = 0; kt2 < 16; ++kt2) {
      int kt = ktbase + kt2;
      bf16x8s ap = *(const bf16x8s*)&Pb[fm & 3][kt*32 + quad*8];
      bf16x8s bw = *(const bf16x8s*)(wrow + kt*32 + quad*8);
      acc = __builtin_amdgcn_mfma_f32_16x16x32_bf16(ap, bw, acc, 0, 0, 0);
    }
    if (quad == 0) {            // D rows 0..3 are the real query rows
      #pragma unroll
      for (int i = 0; i < 4; ++i) opart[w][i][fm] = acc[i];
    }
  }
  __syncthreads();
  if (t < 128) {
    int r = t >> 5, dd = t & 31;
    int nt = dd >> 4, c = dd & 15;
    float sum = opart[nt][r][c] + opart[nt + 2][r][c];
    float hv = (sum >= 0.0f) ? sum : 0.01f*sum;
    long idx = (long)(b*1024 + n0 + r)*256 + h*32 + dd;
    ws[C_OFF + idx] = ldin(x, idx, bf) + hv;   // raw residual row slice
  }
}

// ------- e_out = mean_h attn (from stored mx/rs) + fused rownorm(xa) -------
// Grid 4096: one (b,n) row per block. Rownorm reads raw xa (C region), writes
// B region. e_out recomputed from s1/s2/adj + per-head mx/rs (exact same
// arithmetic/order as before: sum over h of rs*exp(lrelu(s1+s2)-mx)).
__global__ __launch_bounds__(256) void eout_kernel(const int* adj, float* ws,
                                                   void* dout, const int* flagp) {
  const int bf = *flagp;
  int t = threadIdx.x;
  int gid = blockIdx.x;
  int b = gid & 3;
  int n = gid >> 2;
  int row = b*1024 + n;
  int w = t >> 6, lane = t & 63;
  __shared__ float part[8];
  // ---- rownorm (ddof=1, two-pass) of raw xa row ---------------------------
  float v = ws[C_OFF + (long)row*256 + t];
  float s = v;
  #pragma unroll
  for (int off = 32; off > 0; off >>= 1) s += __shfl_xor(s, off);
  if (lane == 0) part[w] = s;
  __syncthreads();
  float mean = (part[0] + part[1] + part[2] + part[3]) * (1.0f/256.0f);
  float d = v - mean;
  float ss = d*d;
  #pragma unroll
  for (int off = 32; off > 0; off >>= 1) ss += __shfl_xor(ss, off);
  if (lane == 0) part[4 + w] = ss;
  __syncthreads();
  float inv = 1.0f / (sqrtf((part[4]+part[5]+part[6]+part[7]) * (1.0f/255.0f)) + 1e-6f);
  ws[B_OFF + (long)row*256 + t] = d * inv;
  // ---- e_out --------------------------------------------------------------
  float s1v[8], mxv[8], rsv[8];
  #pragma unroll
  for (int h = 0; h < 8; ++h) {
    s1v[h] = ws[S1_OFF + h*4096 + row];
    mxv[h] = ws[MX_OFF + h*4096 + row];
    rsv[h] = ws[RS_OFF + h*4096 + row];
  }
  const int* arow = adj + (long)row*1024;
  const float* s2b = ws + S2_OFF + b*1024;
  #pragma unroll
  for (int j = 0; j < 4; ++j) {
    int m = t + 256*j;
    int a = arow[m];
    float acc = 0.0f;
    #pragma unroll
    for (int h = 0; h < 8; ++h) {
      float ev = s1v[h] + s2b[h*4096 + m];
      ev = (ev >= 0.0f) ? ev : 0.1f*ev;
      ev = (a > 0) ? ev : NEGC;
      acc += rsv[h] * __expf(ev - mxv[h]);
    }
    stout(dout, 1048576L + (long)row*1024 + m, 0.125f*acc, bf);
  }
}

// ---------------- column (axis=1) stats, ddof=1 ----------------------------
__global__ __launch_bounds__(256) void colstatsA_kernel(const float* in, float* cs) {
  int t = threadIdx.x;
  int j = blockIdx.x & 15;
  int b = blockIdx.x >> 4;
  float s = 0, ss = 0;
  for (int n = j*64; n < j*64 + 64; ++n) {
    float v = in[(b*1024 + n)*256 + t];
    s += v; ss += v*v;
  }
  cs[(b*16 + j)*256 + t] = s;
  cs[16384 + (b*16 + j)*256 + t] = ss;
}

__global__ __launch_bounds__(256) void colstatsB_kernel(const float* cs, float* st) {
  int t = threadIdx.x;
  int b = blockIdx.x;
  float s = 0, ss = 0;
  for (int j = 0; j < 16; ++j) {
    s  += cs[(b*16 + j)*256 + t];
    ss += cs[16384 + (b*16 + j)*256 + t];
  }
  float mean = s * (1.0f/1024.0f);
  float var = fmaxf((ss - s*mean) * (1.0f/1023.0f), 0.0f);
  st[b*256 + t] = mean;
  st[1024 + b*256 + t] = 1.0f / (sqrtf(var) + 1e-6f);
}

// ---------------- row GEMM, bf16 quad weights ------------------------------
// IN_MODE 0: plain fp32 [row][256]; 1: fp32 + colnorm(st); 2: float-input src
//   permuted (n,b,e)->(b,n,e); 3: fp32 head-major [b][h][n][32]
// RN 1: fused rownorm on output
// OUTM 0: fp32 [row][256]; 1: d_out (dtype per flag); 2: fp32 head-major;
//      3: bf16 head-major; 4: bf16 TRANSPOSED head-major [b][h][d][n]
template<int IN_MODE, int RN, int OUTM>
__global__ __launch_bounds__(256) void gemm_kernel(const void* inp,
    const unsigned short* wmat, const float* bias, const float* st, void* outp,
    const int* flagp) {
  const int bf = *flagp;
  int t = threadIdx.x;
  int r0 = blockIdx.x * 8;
  __shared__ __align__(16) float U[8][256];
  #pragma unroll
  for (int r = 0; r < 8; ++r) {
    int row = r0 + r;
    float v;
    if (IN_MODE == 0) {
      v = ((const float*)inp)[row*256 + t];
    } else if (IN_MODE == 1) {
      int b = row >> 10;
      v = (((const float*)inp)[row*256 + t] - st[b*256 + t]) * st[1024 + b*256 + t];
    } else if (IN_MODE == 2) {
      int b = row >> 10, n = row & 1023;
      v = ldin(inp, (long)(n*4 + b)*256 + t, bf);
    } else {
      int b = row >> 10, n = row & 1023;
      v = ((const float*)inp)[((b*8 + (t >> 5))*1024 + n)*32 + (t & 31)];
    }
    U[r][t] = v;
  }
  __syncthreads();
  float bv = bias[t];
  float acc[8];
  #pragma unroll
  for (int r = 0; r < 8; ++r) acc[r] = bv;
  const ushort4* w4 = (const ushort4*)wmat;
  for (int e4 = 0; e4 < 64; ++e4) {
    ushort4 u = w4[e4*256 + t];
    float w0 = bf2f(u.x), w1 = bf2f(u.y), w2 = bf2f(u.z), w3 = bf2f(u.w);
    #pragma unroll
    for (int r = 0; r < 8; ++r) {
      float4 uu = *(const float4*)&U[r][e4*4];
      acc[r] += uu.x*w0 + uu.y*w1 + uu.z*w2 + uu.w*w3;
    }
  }
  if (RN == 0) {
    #pragma unroll
    for (int r = 0; r < 8; ++r) {
      int row = r0 + r;
      if (OUTM == 0) ((float*)outp)[row*256 + t] = acc[r];
      else if (OUTM == 1) stout(outp, (long)row*256 + t, acc[r], bf);
      else if (OUTM == 2) {
        int b = row >> 10, n = row & 1023;
        ((float*)outp)[((b*8 + (t >> 5))*1024 + n)*32 + (t & 31)] = acc[r];
      } else if (OUTM == 3) {
        int b = row >> 10, n = row & 1023;
        ((unsigned short*)outp)[((b*8 + (t >> 5))*1024 + n)*32 + (t & 31)] = f2bf(acc[r]);
      } else {
        int b = row >> 10, n = row & 1023;
        ((unsigned short*)outp)[((b*8 + (t >> 5))*32 + (t & 31))*1024 + n] = f2bf(acc[r]);
      }
    }
  } else {
    __syncthreads();
    #pragma unroll
    for (int r = 0; r < 8; ++r) U[r][t] = acc[r];
    __syncthreads();
    int w = t >> 6, lane = t & 63;
    for (int rr = w; rr < 8; rr += 4) {
      float vals[4]; float s = 0.0f;
      #pragma unroll
      for (int j = 0; j < 4; ++j) { vals[j] = U[rr][lane + 64*j]; s += vals[j]; }
      #pragma unroll
      for (int off = 32; off > 0; off >>= 1) s += __shfl_xor(s, off);
      float mean = s * (1.0f/256.0f);
      float ss = 0.0f;
      #pragma unroll
      for (int j = 0; j < 4; ++j) { float d = vals[j] - mean; ss += d*d; }
      #pragma unroll
      for (int off = 32; off > 0; off >>= 1) ss += __shfl_xor(ss, off);
      float inv = 1.0f / (sqrtf(ss * (1.0f/255.0f)) + 1e-6f);
      #pragma unroll
      for (int j = 0; j < 4; ++j)
        ((float*)outp)[(r0 + rr)*256 + lane + 64*j] = (vals[j] - mean) * inv;
    }
  }
}

// ---------------- MHA via MFMA, bf16 K/V, 8 q-rows per block ---------------
// GRID MUST BE 4096: 128 row-groups x 4 b x 8 h. h in low 3 bits (XCD-L2).
// Q fp32 head-major [b][h][n][32] at A_OFF (o overwrites q, exclusive slots);
// K bf16 [b][h][n][32] at B_OFF; V^T bf16 [b][h][d][n] at C_OFF.
// mfma_f32_16x16x32_bf16 layouts (m89-verified):
//   A[m=lane&15][k=(lane>>4)*8+j]; B[k=(lane>>4)*8+j][n=lane&15];
//   D col=lane&15, row=(lane>>4)*4+i.
#define SP_CS 36
#define SP_RS 1156
__global__ __launch_bounds__(256) void attn2_kernel(float* ws) {
  int t = threadIdx.x;
  int gid = blockIdx.x;
  int h = gid & 7;
  int b = (gid >> 3) & 3;
  int n0 = (gid >> 5) << 3;   // 8 q-rows per block; gid>>5 in 0..127
  __shared__ __align__(16) float Sp[8*SP_RS];
  __shared__ __align__(16) float opart[4][8][16];
  float* qq = ws + A_OFF;
  const unsigned short* kk = (const unsigned short*)(ws + B_OFF);
  const unsigned short* vt = (const unsigned short*)(ws + C_OFF);
  int base_bh = (b*8 + h)*1024;
  int w = t >> 6, lane = t & 63;
  int m = lane & 15, quad = lane >> 4;
  const float scl = 0.17677669529663687f; // 1/sqrt(32)
  // ---- QK via MFMA: wave w covers keys w*256 .. +255 ----------------------
  {
    const float* qp = qq + (base_bh + n0 + (lane & 7))*32 + quad*8;
    bf16x8s aq;
    #pragma unroll
    for (int j = 0; j < 8; ++j) ((unsigned short*)&aq)[j] = f2bf(qp[j]);
    f32x4 zero = {0.0f, 0.0f, 0.0f, 0.0f};
    #pragma unroll
    for (int kt = 0; kt < 16; ++kt) {
      int kbase = w*256 + kt*16;
      bf16x8s bk = *(const bf16x8s*)(kk + (base_bh + kbase + m)*32 + quad*8);
      f32x4 d = __builtin_amdgcn_mfma_f32_16x16x32_bf16(aq, bk, zero, 0, 0, 0);
      if (lane < 32) {
        int key = kbase + m;
        int a = (key >> 5)*SP_CS + (key & 31);
        #pragma unroll
        for (int i = 0; i < 4; ++i)
          Sp[(quad*4 + i)*SP_RS + a] = d[i] * scl;
      }
    }
  }
  __syncthreads();
  // ---- softmax: wave w handles rows w and w+4 -----------------------------
  #pragma unroll
  for (int rr = 0; rr < 2; ++rr) {
    float* Sr = Sp + (w + 4*rr)*SP_RS;
    float mx = -3.4e38f;
    #pragma unroll
    for (int j = 0; j < 16; ++j) {
      int mm = lane + 64*j;
      mx = fmaxf(mx, Sr[(mm >> 5)*SP_CS + (mm & 31)]);
    }
    #pragma unroll
    for (int off = 32; off > 0; off >>= 1) mx = fmaxf(mx, __shfl_xor(mx, off));
    float s = 0.0f;
    #pragma unroll
    for (int j = 0; j < 16; ++j) {
      int mm = lane + 64*j;
      int a = (mm >> 5)*SP_CS + (mm & 31);
      float p = __expf(Sr[a] - mx);
      Sr[a] = p;
      s += p;
    }
    #pragma unroll
    for (int off = 32; off > 0; off >>= 1) s += __shfl_xor(s, off);
    float rs = 1.0f / s;
    #pragma unroll
    for (int j = 0; j < 16; ++j) {
      int mm = lane + 64*j;
      Sr[(mm >> 5)*SP_CS + (mm & 31)] *= rs;
    }
  }
  __syncthreads();
  // ---- PV via MFMA: wave w -> N-tile (w&1), k-tiles (w>>1)*16 .. +15 ------
  {
    int ntile = w & 1;
    int ktbase = (w >> 1) * 16;
    int vd = ntile*16 + m;
    const unsigned short* vrow = vt + base_bh*32 + vd*1024;
    f32x4 acc = {0.0f, 0.0f, 0.0f, 0.0f};
    #pragma unroll
    for (int kt2 = 0; kt2 < 16; ++kt2) {
      int kt = ktbase + kt2;
      const float* pp = Sp + (lane & 7)*SP_RS + kt*SP_CS + quad*8;
      bf16x8s ap;
      #pragma unroll
      for (int j = 0; j < 8; ++j) ((unsigned short*)&ap)[j] = f2bf(pp[j]);
      bf16x8s bv = *(const bf16x8s*)(vrow + kt*32 + quad*8);
      acc = __builtin_amdgcn_mfma_f32_16x16x32_bf16(ap, bv, acc, 0, 0, 0);
    }
    if (lane < 32) {
      #pragma unroll
      for (int i = 0; i < 4; ++i)
        opart[w][quad*4 + i][m] = acc[i];
    }
  }
  __syncthreads();
  {
    int r = t >> 5, d = t & 31;
    int nt = d >> 4, c = d & 15;
    float sum = opart[nt][r][c] + opart[nt + 2][r][c];
    qq[(base_bh + n0 + r)*32 + d] = sum;   // o over q (own slots)
  }
}

extern "C" void kernel_launch(void* const* d_in, const int* in_sizes, int n_in,
                              void* d_out, int out_size, void* d_ws, size_t ws_size,
                              hipStream_t stream) {
  const void* x   = d_in[0];
  const void* src = d_in[1];
  const int* adj  = (const int*)d_in[2];
  const void* wg  = d_in[3];
  const void* a1  = d_in[4];
  const void* a2  = d_in[5];
  const void* lw  = d_in[6];
  const void* lb  = d_in[7];
  const void* ipw = d_in[8];
  const void* ipb = d_in[9];
  const void* opw = d_in[10];
  const void* opb = d_in[11];
  float* ws = (float*)d_ws;
  const unsigned short* wbf = (const unsigned short*)d_ws;
  int* flagp = (int*)(ws + FLAG_F);

  detect_kernel<<<1, 64, 0, stream>>>((const unsigned short*)x, flagp);
  prep_kernel<<<dim3(256, 7), 256, 0, stream>>>(wg, lw, ipw, opw, lb, ipb, opb,
                                                a1, a2, ws, flagp);
  whs_kernel<<<512, 256, 0, stream>>>(x, ws, flagp);
  attn1a_kernel<<<8192, 256, 0, stream>>>(x, adj, ws, flagp);   // xa -> C, mx/rs
  eout_kernel<<<4096, 256, 0, stream>>>(adj, ws, d_out, flagp); // e_out; rownorm -> B
  colstatsA_kernel<<<64, 256, 0, stream>>>(ws + B_OFF, ws + CS_OFF);
  colstatsB_kernel<<<4, 256, 0, stream>>>(ws + CS_OFF, ws + ST1_OFF);
  gemm_kernel<1,1,0><<<512, 256, 0, stream>>>(ws + B_OFF, wbf + 1*65536,
      ws + BIAS_OFF, ws + ST1_OFF, ws + C_OFF, flagp);
  colstatsA_kernel<<<64, 256, 0, stream>>>(ws + C_OFF, ws + CS_OFF);
  colstatsB_kernel<<<4, 256, 0, stream>>>(ws + CS_OFF, ws + ST2_OFF);
  gemm_kernel<1,0,2><<<512, 256, 0, stream>>>(ws + C_OFF, wbf + 2*65536,
      ws + BIAS_OFF + 256, ws + ST2_OFF, ws + A_OFF, flagp);   // Q fp32 hm
  gemm_kernel<1,0,3><<<512, 256, 0, stream>>>(ws + C_OFF, wbf + 3*65536,
      ws + BIAS_OFF + 512, ws + ST2_OFF, ws + B_OFF, flagp);   // K bf16 hm
  gemm_kernel<2,0,4><<<512, 256, 0, stream>>>(src, wbf + 4*65536,
      ws + BIAS_OFF + 768, nullptr, ws + C_OFF, flagp);        // V^T bf16 hm
  attn2_kernel<<<4096, 256, 0, stream>>>(ws);                  // o -> A_OFF
  gemm_kernel<3,0,1><<<512, 256, 0, stream>>>(ws + A_OFF, wbf + 5*65536,
      ws + BIAS_OFF + 1024, nullptr, d_out, flagp);            // out-proj
}

// Round 2
// 345.757 us; speedup vs baseline: 1.0695x; 1.0695x over previous
//
#include <hip/hip_runtime.h>
#include <hip/hip_bf16.h>

// B=4, N=1024, E=256, H=8, D=32. Float tensors may be bf16 OR fp32 in d_in /
// d_out (detected at runtime on-device); adj is int32.
// Output: x_out [4,1024,256] then e_out [4,1024,1024] (element offsets).
//
// ws float offsets:
//   [0 .. 196608)   : 6 weight matrices, transposed, bf16, quad-interleaved
//                     matrix m at ushort offset m*65536; element (e,o) at
//                     ((e>>2)*256 + o)*4 + (e&3).  m: 0=Wcat 1=LIN 2=WQ 3=WK 4=WV 5=WO
#define BIAS_OFF 196608   // lin_b, bq, bk, bv, bo, a1, a2  (7*256 fp32)
#define S1_OFF   198400   // [h][4096]
#define S2_OFF   231168
#define CS_OFF   263936   // 32768: column partial sums+sumsq (reused twice)
#define ST1_OFF  296704   // mean[1024] + inv[1024]
#define ST2_OFF  298752
#define A_OFF    300800   // WhT bf16 [h][b][d][n] (2 MB) -> later Q,o fp32 head-major
#define MX_OFF   825088   // A_OFF+524288: softmax row max  [h][4096] (dead before Q)
#define RS_OFF   857856   // softmax row 1/sum              [h][4096]
#define PK_OFF   890624   // packed adj bitmask: [4096 rows][16 u64] = 512 KB (dead before Q)
#define B_OFF    1349376  // 4 MB: rownorm(xa)     -> later K bf16 head-major [b][h][n][32]
#define C_OFF    2397952  // 4 MB: raw xa, then rownorm(lin) -> later V^T bf16 hm [b][h][d][n]
#define FLAG_F   3446528  // int: 1 = bf16 tensors, 0 = fp32 tensors
// end 3446529 floats = 13.8 MB

#define NEGC (-9.0e15f)

typedef __attribute__((ext_vector_type(8))) short bf16x8s;
typedef __attribute__((ext_vector_type(4))) float f32x4;

static __device__ __forceinline__ float bf2f(unsigned short u) {
  union { unsigned int i; float f; } v; v.i = ((unsigned int)u) << 16; return v.f;
}
static __device__ __forceinline__ unsigned short f2bf(float f) {
  union { float f; unsigned int u; } v; v.f = f;
  unsigned int r = (v.u + 0x7FFFu + ((v.u >> 16) & 1u)) >> 16;   // RNE
  return (unsigned short)r;
}
static __device__ __forceinline__ float ldin(const void* p, long i, int bf) {
  return bf ? bf2f(((const unsigned short*)p)[i]) : ((const float*)p)[i];
}
static __device__ __forceinline__ unsigned short rdbf(const void* p, long i, int bf) {
  if (bf) return ((const unsigned short*)p)[i];
  return f2bf(((const float*)p)[i]);
}
static __device__ __forceinline__ void stout(void* p, long i, float v, int bf) {
  if (bf) ((unsigned short*)p)[i] = f2bf(v);
  else    ((float*)p)[i] = v;
}

// ---------------- dtype detector -------------------------------------------
__global__ __launch_bounds__(64) void detect_kernel(const unsigned short* x, int* flag) {
  int lane = threadIdx.x;
  unsigned short u = x[2 * lane];
  int e = (u >> 7) & 0xFF;
  bool good = (e >= 100 && e <= 140);
  unsigned long long m = __ballot(good);
  if (lane == 0) *flag = (__popcll(m) >= 48) ? 1 : 0;
}

// ---------------- adj -> bitmask: [row][16 u64], bit m%64 of word m/64 -----
__global__ __launch_bounds__(256) void packadj_kernel(const int* adj,
                                                      unsigned long long* pk) {
  int t = threadIdx.x, w = t >> 6, lane = t & 63;
  long row = blockIdx.x;            // 4096 rows
  #pragma unroll
  for (int j = 0; j < 4; ++j) {
    int m = t + 256*j;              // wave covers bits [w*64+256j .. +63]
    bool bit = adj[row*1024 + m] > 0;
    unsigned long long mask = __ballot(bit);
    if (lane == 0) pk[row*16 + w + 4*j] = mask;
  }
}

// ---------------- prep: weights -> transposed quad bf16; biases -> fp32 ----
__global__ __launch_bounds__(256) void prep_kernel(
    const void* wg, const void* lin_w, const void* inp_w, const void* out_w,
    const void* lin_b, const void* inp_b, const void* out_b,
    const void* a1, const void* a2, float* ws, const int* flagp) {
  const int bf = *flagp;
  unsigned short* wbf = (unsigned short*)ws;
  int t = threadIdx.x;
  int f = blockIdx.x;
  int m = blockIdx.y;
  int dst = m*65536 + ((f >> 2)*256 + t)*4 + (f & 3);
  if (m == 0) {
    int h = t >> 5, d = t & 31;
    wbf[dst] = rdbf(wg, h*8192 + f*32 + d, bf);
  } else if (m == 1) wbf[dst] = rdbf(lin_w, t*256 + f, bf);
  else if (m == 2)   wbf[dst] = rdbf(inp_w, t*256 + f, bf);
  else if (m == 3)   wbf[dst] = rdbf(inp_w, (256 + t)*256 + f, bf);
  else if (m == 4)   wbf[dst] = rdbf(inp_w, (512 + t)*256 + f, bf);
  else if (m == 5)   wbf[dst] = rdbf(out_w, t*256 + f, bf);
  else if (f == 0) {
    ws[BIAS_OFF + t]        = ldin(lin_b, t, bf);
    ws[BIAS_OFF + 256 + t]  = ldin(inp_b, t, bf);
    ws[BIAS_OFF + 512 + t]  = ldin(inp_b, 256 + t, bf);
    ws[BIAS_OFF + 768 + t]  = ldin(inp_b, 512 + t, bf);
    ws[BIAS_OFF + 1024 + t] = ldin(out_b, t, bf);
    ws[BIAS_OFF + 1280 + t] = ldin(a1, t, bf);
    ws[BIAS_OFF + 1536 + t] = ldin(a2, t, bf);
  }
}

// -------- Wh = x @ Wcat -> WhT bf16 [h][b][d][n]; s1/s2 head reductions ----
__global__ __launch_bounds__(256) void whs_kernel(const void* x, float* ws,
                                                  const int* flagp) {
  const int bf = *flagp;
  int t = threadIdx.x;
  int r0 = blockIdx.x * 8;
  __shared__ __align__(16) float U[8][256];
  #pragma unroll
  for (int r = 0; r < 8; ++r)
    U[r][t] = ldin(x, (long)(r0 + r)*256 + t, bf);
  __syncthreads();
  const ushort4* w4 = (const ushort4*)ws;
  float acc[8] = {0,0,0,0,0,0,0,0};
  for (int e4 = 0; e4 < 64; ++e4) {
    ushort4 u = w4[e4*256 + t];
    float w0 = bf2f(u.x), w1 = bf2f(u.y), w2 = bf2f(u.z), w3 = bf2f(u.w);
    #pragma unroll
    for (int r = 0; r < 8; ++r) {
      float4 uu = *(const float4*)&U[r][e4*4];
      acc[r] += uu.x*w0 + uu.y*w1 + uu.z*w2 + uu.w*w3;
    }
  }
  int h = t >> 5, d = t & 31;
  float a1v = ws[BIAS_OFF + 1280 + t];
  float a2v = ws[BIAS_OFF + 1536 + t];
  unsigned short wvals[8];
  #pragma unroll
  for (int r = 0; r < 8; ++r) {
    int row = r0 + r;
    wvals[r] = f2bf(acc[r]);
    float p1 = acc[r]*a1v, p2 = acc[r]*a2v;
    #pragma unroll
    for (int off = 16; off > 0; off >>= 1) {
      p1 += __shfl_xor(p1, off, 32);
      p2 += __shfl_xor(p2, off, 32);
    }
    if (d == 0) {
      ws[S1_OFF + h*4096 + row] = p1;
      ws[S2_OFF + h*4096 + row] = p2;
    }
  }
  // WhT[h][b][d][n], 8 contiguous n per thread (16B store)
  {
    unsigned short* wht = (unsigned short*)(ws + A_OFF);
    int bb = r0 >> 10, nn = r0 & 1023;
    *(bf16x8s*)(wht + ((long)((h*4 + bb)*32 + d))*1024 + nn) = *(bf16x8s*)wvals;
  }
}

// ------- graph attention, head-split, 8 rows/block -------------------------
// Grid 4096 = 4b x 128 groups x 8h; h in low 3 bits (XCD-L2 locality on WhT).
// adj from packed bitmask (scalar loads). Softmax register-resident: wave w
// owns rows w and w+4 (sequential). P bf16 in Pb (8 real rows, dup x2 in the
// 16-row MFMA A-tile). PV via mfma_f32_16x16x32_bf16 against WhT. Writes:
//   C region: raw xa slice  xa[b,n,h*32+d] = x + leaky(PV)
//   MX/RS: per-(h,row) softmax max and 1/sum (consumed by eout_kernel)
#define PB_S 1032    // Pb row stride (ushorts); 2064B = 129*16, rows +4 banks
__global__ __launch_bounds__(256) void attn1a_kernel(const void* x, float* ws,
                                                     const int* flagp) {
  const int bf = *flagp;
  int t = threadIdx.x;
  int gid = blockIdx.x;
  int h = gid & 7;
  int b = (gid >> 3) & 3;
  int n0 = (gid >> 5) * 8;
  __shared__ __align__(16) float s2s[1024];
  __shared__ __align__(16) unsigned short Pb[8][PB_S];
  __shared__ __align__(16) float opart[4][8][16];
  int w = t >> 6, lane = t & 63;
  int fm = lane & 15, quad = lane >> 4;
  const unsigned long long* pk = (const unsigned long long*)(ws + PK_OFF);
  const float* s2p = ws + S2_OFF + h*4096 + b*1024;
  #pragma unroll
  for (int j = 0; j < 4; ++j) s2s[t + 256*j] = s2p[t + 256*j];
  __syncthreads();
  // ---- softmax rows (n0+w) and (n0+w+4), head h: register resident --------
  #pragma unroll
  for (int rr = 0; rr < 2; ++rr) {
    int r = w + 4*rr;
    int rowi = __builtin_amdgcn_readfirstlane(b*1024 + n0 + r);
    const unsigned long long* prow = pk + (long)rowi * 16;   // wave-uniform
    float s1v = ws[S1_OFF + h*4096 + rowi];
    float p[16];
    float mx = -3.4e38f;
    #pragma unroll
    for (int j = 0; j < 16; ++j) {
      int m = lane + 64*j;
      float ev = s1v + s2s[m];
      ev = (ev >= 0.0f) ? ev : 0.1f*ev;
      ev = ((prow[j] >> lane) & 1ull) ? ev : NEGC;
      p[j] = ev;
      mx = fmaxf(mx, ev);
    }
    #pragma unroll
    for (int off = 32; off > 0; off >>= 1) mx = fmaxf(mx, __shfl_xor(mx, off));
    float s = 0.0f;
    #pragma unroll
    for (int j = 0; j < 16; ++j) { p[j] = __expf(p[j] - mx); s += p[j]; }
    #pragma unroll
    for (int off = 32; off > 0; off >>= 1) s += __shfl_xor(s, off);
    float rs = 1.0f / s;
    #pragma unroll
    for (int j = 0; j < 16; ++j)
      Pb[r][lane + 64*j] = f2bf(p[j] * rs);
    if (lane == 0) {
      ws[MX_OFF + h*4096 + rowi] = mx;
      ws[RS_OFF + h*4096 + rowi] = rs;
    }
  }
  __syncthreads();
  // ---- PV via MFMA: wave w -> ntile (w&1), k-tiles (w>>1)*16 .. +15 -------
  {
    const unsigned short* wht = (const unsigned short*)(ws + A_OFF);
    int ntile = w & 1;
    int ktbase = (w >> 1) * 16;
    int vd = ntile*16 + fm;
    const unsigned short* wrow = wht + ((long)((h*4 + b)*32 + vd))*1024;
    f32x4 acc = {0.0f, 0.0f, 0.0f, 0.0f};
    #pragma unroll
    for (int kt2 = 0; kt2 < 16; ++kt2) {
      int kt = ktbase + kt2;
      bf16x8s ap = *(const bf16x8s*)&Pb[fm & 7][kt*32 + quad*8];
      bf16x8s bw = *(const bf16x8s*)(wrow + kt*32 + quad*8);
      acc = __builtin_amdgcn_mfma_f32_16x16x32_bf16(ap, bw, acc, 0, 0, 0);
    }
    if (quad < 2) {             // D rows 0..7 are the real query rows
      #pragma unroll
      for (int i = 0; i < 4; ++i) opart[w][quad*4 + i][fm] = acc[i];
    }
  }
  __syncthreads();
  {
    int r = t >> 5, dd = t & 31;
    int nt = dd >> 4, c = dd & 15;
    float sum = opart[nt][r][c] + opart[nt + 2][r][c];
    float hv = (sum >= 0.0f) ? sum : 0.01f*sum;
    long idx = (long)(b*1024 + n0 + r)*256 + h*32 + dd;
    ws[C_OFF + idx] = ldin(x, idx, bf) + hv;   // raw residual row slice
  }
}

// ------- e_out = mean_h attn (from stored mx/rs) + fused rownorm(xa) -------
// Grid 4096: one (b,n) row per block. Rownorm reads raw xa (C region), writes
// B region. e_out recomputed from s1/s2/packed-adj + per-head mx/rs (exact
// same arithmetic/order as before: sum over h of rs*exp(lrelu(s1+s2)-mx)).
__global__ __launch_bounds__(256) void eout_kernel(float* ws, void* dout,
                                                   const int* flagp) {
  const int bf = *flagp;
  int t = threadIdx.x;
  int gid = blockIdx.x;
  int b = gid & 3;
  int n = gid >> 2;
  int row = b*1024 + n;
  int w = t >> 6, lane = t & 63;
  __shared__ float part[8];
  const unsigned long long* pk = (const unsigned long long*)(ws + PK_OFF);
  const unsigned long long* prow = pk + (long)row * 16;
  // ---- rownorm (ddof=1, two-pass) of raw xa row ---------------------------
  float v = ws[C_OFF + (long)row*256 + t];
  float s = v;
  #pragma unroll
  for (int off = 32; off > 0; off >>= 1) s += __shfl_xor(s, off);
  if (lane == 0) part[w] = s;
  __syncthreads();
  float mean = (part[0] + part[1] + part[2] + part[3]) * (1.0f/256.0f);
  float d = v - mean;
  float ss = d*d;
  #pragma unroll
  for (int off = 32; off > 0; off >>= 1) ss += __shfl_xor(ss, off);
  if (lane == 0) part[4 + w] = ss;
  __syncthreads();
  float inv = 1.0f / (sqrtf((part[4]+part[5]+part[6]+part[7]) * (1.0f/255.0f)) + 1e-6f);
  ws[B_OFF + (long)row*256 + t] = d * inv;
  // ---- e_out --------------------------------------------------------------
  float s1v[8], mxv[8], rsv[8];
  #pragma unroll
  for (int h = 0; h < 8; ++h) {
    s1v[h] = ws[S1_OFF + h*4096 + row];
    mxv[h] = ws[MX_OFF + h*4096 + row];
    rsv[h] = ws[RS_OFF + h*4096 + row];
  }
  const float* s2b = ws + S2_OFF + b*1024;
  #pragma unroll
  for (int j = 0; j < 4; ++j) {
    int m = t + 256*j;
    bool a = (prow[w + 4*j] >> lane) & 1ull;   // bit m: word (m>>6)=w+4j, bit lane
    float acc = 0.0f;
    #pragma unroll
    for (int h = 0; h < 8; ++h) {
      float ev = s1v[h] + s2b[h*4096 + m];
      ev = (ev >= 0.0f) ? ev : 0.1f*ev;
      ev = a ? ev : NEGC;
      acc += rsv[h] * __expf(ev - mxv[h]);
    }
    stout(dout, 1048576L + (long)row*1024 + m, 0.125f*acc, bf);
  }
}

// ---------------- column (axis=1) stats, ddof=1 ----------------------------
__global__ __launch_bounds__(256) void colstatsA_kernel(const float* in, float* cs) {
  int t = threadIdx.x;
  int j = blockIdx.x & 15;
  int b = blockIdx.x >> 4;
  float s = 0, ss = 0;
  for (int n = j*64; n < j*64 + 64; ++n) {
    float v = in[(b*1024 + n)*256 + t];
    s += v; ss += v*v;
  }
  cs[(b*16 + j)*256 + t] = s;
  cs[16384 + (b*16 + j)*256 + t] = ss;
}

__global__ __launch_bounds__(256) void colstatsB_kernel(const float* cs, float* st) {
  int t = threadIdx.x;
  int b = blockIdx.x;
  float s = 0, ss = 0;
  for (int j = 0; j < 16; ++j) {
    s  += cs[(b*16 + j)*256 + t];
    ss += cs[16384 + (b*16 + j)*256 + t];
  }
  float mean = s * (1.0f/1024.0f);
  float var = fmaxf((ss - s*mean) * (1.0f/1023.0f), 0.0f);
  st[b*256 + t] = mean;
  st[1024 + b*256 + t] = 1.0f / (sqrtf(var) + 1e-6f);
}

// ---------------- row GEMM, bf16 quad weights ------------------------------
// IN_MODE 0: plain fp32 [row][256]; 1: fp32 + colnorm(st); 2: float-input src
//   permuted (n,b,e)->(b,n,e); 3: fp32 head-major [b][h][n][32]
// RN 1: fused rownorm on output
// OUTM 0: fp32 [row][256]; 1: d_out (dtype per flag); 2: fp32 head-major;
//      3: bf16 head-major; 4: bf16 TRANSPOSED head-major [b][h][d][n]
template<int IN_MODE, int RN, int OUTM>
__global__ __launch_bounds__(256) void gemm_kernel(const void* inp,
    const unsigned short* wmat, const float* bias, const float* st, void* outp,
    const int* flagp) {
  const int bf = *flagp;
  int t = threadIdx.x;
  int r0 = blockIdx.x * 8;
  __shared__ __align__(16) float U[8][256];
  #pragma unroll
  for (int r = 0; r < 8; ++r) {
    int row = r0 + r;
    float v;
    if (IN_MODE == 0) {
      v = ((const float*)inp)[row*256 + t];
    } else if (IN_MODE == 1) {
      int b = row >> 10;
      v = (((const float*)inp)[row*256 + t] - st[b*256 + t]) * st[1024 + b*256 + t];
    } else if (IN_MODE == 2) {
      int b = row >> 10, n = row & 1023;
      v = ldin(inp, (long)(n*4 + b)*256 + t, bf);
    } else {
      int b = row >> 10, n = row & 1023;
      v = ((const float*)inp)[((b*8 + (t >> 5))*1024 + n)*32 + (t & 31)];
    }
    U[r][t] = v;
  }
  __syncthreads();
  float bv = bias[t];
  float acc[8];
  #pragma unroll
  for (int r = 0; r < 8; ++r) acc[r] = bv;
  const ushort4* w4 = (const ushort4*)wmat;
  for (int e4 = 0; e4 < 64; ++e4) {
    ushort4 u = w4[e4*256 + t];
    float w0 = bf2f(u.x), w1 = bf2f(u.y), w2 = bf2f(u.z), w3 = bf2f(u.w);
    #pragma unroll
    for (int r = 0; r < 8; ++r) {
      float4 uu = *(const float4*)&U[r][e4*4];
      acc[r] += uu.x*w0 + uu.y*w1 + uu.z*w2 + uu.w*w3;
    }
  }
  if (RN == 0) {
    #pragma unroll
    for (int r = 0; r < 8; ++r) {
      int row = r0 + r;
      if (OUTM == 0) ((float*)outp)[row*256 + t] = acc[r];
      else if (OUTM == 1) stout(outp, (long)row*256 + t, acc[r], bf);
      else if (OUTM == 2) {
        int b = row >> 10, n = row & 1023;
        ((float*)outp)[((b*8 + (t >> 5))*1024 + n)*32 + (t & 31)] = acc[r];
      } else if (OUTM == 3) {
        int b = row >> 10, n = row & 1023;
        ((unsigned short*)outp)[((b*8 + (t >> 5))*1024 + n)*32 + (t & 31)] = f2bf(acc[r]);
      } else {
        int b = row >> 10, n = row & 1023;
        ((unsigned short*)outp)[((b*8 + (t >> 5))*32 + (t & 31))*1024 + n] = f2bf(acc[r]);
      }
    }
  } else {
    __syncthreads();
    #pragma unroll
    for (int r = 0; r < 8; ++r) U[r][t] = acc[r];
    __syncthreads();
    int w = t >> 6, lane = t & 63;
    for (int rr = w; rr < 8; rr += 4) {
      float vals[4]; float s = 0.0f;
      #pragma unroll
      for (int j = 0; j < 4; ++j) { vals[j] = U[rr][lane + 64*j]; s += vals[j]; }
      #pragma unroll
      for (int off = 32; off > 0; off >>= 1) s += __shfl_xor(s, off);
      float mean = s * (1.0f/256.0f);
      float ss = 0.0f;
      #pragma unroll
      for (int j = 0; j < 4; ++j) { float d = vals[j] - mean; ss += d*d; }
      #pragma unroll
      for (int off = 32; off > 0; off >>= 1) ss += __shfl_xor(ss, off);
      float inv = 1.0f / (sqrtf(ss * (1.0f/255.0f)) + 1e-6f);
      #pragma unroll
      for (int j = 0; j < 4; ++j)
        ((float*)outp)[(r0 + rr)*256 + lane + 64*j] = (vals[j] - mean) * inv;
    }
  }
}

// ---------------- MHA via MFMA, bf16 K/V, 8 q-rows per block ---------------
// GRID MUST BE 4096: 128 row-groups x 4 b x 8 h. h in low 3 bits (XCD-L2).
// Q fp32 head-major [b][h][n][32] at A_OFF (o overwrites q, exclusive slots);
// K bf16 [b][h][n][32] at B_OFF; V^T bf16 [b][h][d][n] at C_OFF.
// mfma_f32_16x16x32_bf16 layouts (m89-verified):
//   A[m=lane&15][k=(lane>>4)*8+j]; B[k=(lane>>4)*8+j][n=lane&15];
//   D col=lane&15, row=(lane>>4)*4+i.
#define SP_CS 36
#define SP_RS 1156
__global__ __launch_bounds__(256) void attn2_kernel(float* ws) {
  int t = threadIdx.x;
  int gid = blockIdx.x;
  int h = gid & 7;
  int b = (gid >> 3) & 3;
  int n0 = (gid >> 5) << 3;   // 8 q-rows per block; gid>>5 in 0..127
  __shared__ __align__(16) float Sp[8*SP_RS];
  __shared__ __align__(16) float opart[4][8][16];
  float* qq = ws + A_OFF;
  const unsigned short* kk = (const unsigned short*)(ws + B_OFF);
  const unsigned short* vt = (const unsigned short*)(ws + C_OFF);
  int base_bh = (b*8 + h)*1024;
  int w = t >> 6, lane = t & 63;
  int m = lane & 15, quad = lane >> 4;
  const float scl = 0.17677669529663687f; // 1/sqrt(32)
  // ---- QK via MFMA: wave w covers keys w*256 .. +255 ----------------------
  {
    const float* qp = qq + (base_bh + n0 + (lane & 7))*32 + quad*8;
    bf16x8s aq;
    #pragma unroll
    for (int j = 0; j < 8; ++j) ((unsigned short*)&aq)[j] = f2bf(qp[j]);
    f32x4 zero = {0.0f, 0.0f, 0.0f, 0.0f};
    #pragma unroll
    for (int kt = 0; kt < 16; ++kt) {
      int kbase = w*256 + kt*16;
      bf16x8s bk = *(const bf16x8s*)(kk + (base_bh + kbase + m)*32 + quad*8);
      f32x4 d = __builtin_amdgcn_mfma_f32_16x16x32_bf16(aq, bk, zero, 0, 0, 0);
      if (lane < 32) {
        int key = kbase + m;
        int a = (key >> 5)*SP_CS + (key & 31);
        #pragma unroll
        for (int i = 0; i < 4; ++i)
          Sp[(quad*4 + i)*SP_RS + a] = d[i] * scl;
      }
    }
  }
  __syncthreads();
  // ---- softmax: wave w handles rows w and w+4 -----------------------------
  #pragma unroll
  for (int rr = 0; rr < 2; ++rr) {
    float* Sr = Sp + (w + 4*rr)*SP_RS;
    float mx = -3.4e38f;
    #pragma unroll
    for (int j = 0; j < 16; ++j) {
      int mm = lane + 64*j;
      mx = fmaxf(mx, Sr[(mm >> 5)*SP_CS + (mm & 31)]);
    }
    #pragma unroll
    for (int off = 32; off > 0; off >>= 1) mx = fmaxf(mx, __shfl_xor(mx, off));
    float s = 0.0f;
    #pragma unroll
    for (int j = 0; j < 16; ++j) {
      int mm = lane + 64*j;
      int a = (mm >> 5)*SP_CS + (mm & 31);
      float p = __expf(Sr[a] - mx);
      Sr[a] = p;
      s += p;
    }
    #pragma unroll
    for (int off = 32; off > 0; off >>= 1) s += __shfl_xor(s, off);
    float rs = 1.0f / s;
    #pragma unroll
    for (int j = 0; j < 16; ++j) {
      int mm = lane + 64*j;
      Sr[(mm >> 5)*SP_CS + (mm & 31)] *= rs;
    }
  }
  __syncthreads();
  // ---- PV via MFMA: wave w -> N-tile (w&1), k-tiles (w>>1)*16 .. +15 ------
  {
    int ntile = w & 1;
    int ktbase = (w >> 1) * 16;
    int vd = ntile*16 + m;
    const unsigned short* vrow = vt + base_bh*32 + vd*1024;
    f32x4 acc = {0.0f, 0.0f, 0.0f, 0.0f};
    #pragma unroll
    for (int kt2 = 0; kt2 < 16; ++kt2) {
      int kt = ktbase + kt2;
      const float* pp = Sp + (lane & 7)*SP_RS + kt*SP_CS + quad*8;
      bf16x8s ap;
      #pragma unroll
      for (int j = 0; j < 8; ++j) ((unsigned short*)&ap)[j] = f2bf(pp[j]);
      bf16x8s bv = *(const bf16x8s*)(vrow + kt*32 + quad*8);
      acc = __builtin_amdgcn_mfma_f32_16x16x32_bf16(ap, bv, acc, 0, 0, 0);
    }
    if (lane < 32) {
      #pragma unroll
      for (int i = 0; i < 4; ++i)
        opart[w][quad*4 + i][m] = acc[i];
    }
  }
  __syncthreads();
  {
    int r = t >> 5, d = t & 31;
    int nt = d >> 4, c = d & 15;
    float sum = opart[nt][r][c] + opart[nt + 2][r][c];
    qq[(base_bh + n0 + r)*32 + d] = sum;   // o over q (own slots)
  }
}

extern "C" void kernel_launch(void* const* d_in, const int* in_sizes, int n_in,
                              void* d_out, int out_size, void* d_ws, size_t ws_size,
                              hipStream_t stream) {
  const void* x   = d_in[0];
  const void* src = d_in[1];
  const int* adj  = (const int*)d_in[2];
  const void* wg  = d_in[3];
  const void* a1  = d_in[4];
  const void* a2  = d_in[5];
  const void* lw  = d_in[6];
  const void* lb  = d_in[7];
  const void* ipw = d_in[8];
  const void* ipb = d_in[9];
  const void* opw = d_in[10];
  const void* opb = d_in[11];
  float* ws = (float*)d_ws;
  const unsigned short* wbf = (const unsigned short*)d_ws;
  int* flagp = (int*)(ws + FLAG_F);

  detect_kernel<<<1, 64, 0, stream>>>((const unsigned short*)x, flagp);
  prep_kernel<<<dim3(256, 7), 256, 0, stream>>>(wg, lw, ipw, opw, lb, ipb, opb,
                                                a1, a2, ws, flagp);
  packadj_kernel<<<4096, 256, 0, stream>>>(adj,
      (unsigned long long*)(ws + PK_OFF));
  whs_kernel<<<512, 256, 0, stream>>>(x, ws, flagp);
  attn1a_kernel<<<4096, 256, 0, stream>>>(x, ws, flagp);       // xa -> C, mx/rs
  eout_kernel<<<4096, 256, 0, stream>>>(ws, d_out, flagp);     // e_out; rownorm -> B
  colstatsA_kernel<<<64, 256, 0, stream>>>(ws + B_OFF, ws + CS_OFF);
  colstatsB_kernel<<<4, 256, 0, stream>>>(ws + CS_OFF, ws + ST1_OFF);
  gemm_kernel<1,1,0><<<512, 256, 0, stream>>>(ws + B_OFF, wbf + 1*65536,
      ws + BIAS_OFF, ws + ST1_OFF, ws + C_OFF, flagp);
  colstatsA_kernel<<<64, 256, 0, stream>>>(ws + C_OFF, ws + CS_OFF);
  colstatsB_kernel<<<4, 256, 0, stream>>>(ws + CS_OFF, ws + ST2_OFF);
  gemm_kernel<1,0,2><<<512, 256, 0, stream>>>(ws + C_OFF, wbf + 2*65536,
      ws + BIAS_OFF + 256, ws + ST2_OFF, ws + A_OFF, flagp);   // Q fp32 hm
  gemm_kernel<1,0,3><<<512, 256, 0, stream>>>(ws + C_OFF, wbf + 3*65536,
      ws + BIAS_OFF + 512, ws + ST2_OFF, ws + B_OFF, flagp);   // K bf16 hm
  gemm_kernel<2,0,4><<<512, 256, 0, stream>>>(src, wbf + 4*65536,
      ws + BIAS_OFF + 768, nullptr, ws + C_OFF, flagp);        // V^T bf16 hm
  attn2_kernel<<<4096, 256, 0, stream>>>(ws);                  // o -> A_OFF
  gemm_kernel<3,0,1><<<512, 256, 0, stream>>>(ws + A_OFF, wbf + 5*65536,
      ws + BIAS_OFF + 1024, nullptr, d_out, flagp);            // out-proj
}